// Round 2
// baseline (498.433 us; speedup 1.0000x reference)
//
#include <hip/hip_runtime.h>

#define B_ROWS 16384
#define K_DIM  128
#define C_CLS  32

// ws layout (bytes)
#define O_COUNTS   0
#define O_FIRST    256
#define O_RANK     512
#define O_OFFS     768
#define O_KLACC    1024
#define O_LD2      1152
#define O_COUNTSF  1280
#define O_COLSUM   2048            // 32*128*4 = 16384
#define O_MU       18432           // 16384
#define O_LIST     34816           // 16384*4 = 65536
#define O_S        102400          // 32*16384*4 = 2 MiB
#define O_INV      (102400 + 2097152)

// ---------------------------------------------------------------------------
// K1: counts, first-occurrence, appearance rank, offsets, class bucket list.
// Single block so no grid sync needed. 1024 threads, 16 rows each.
// ---------------------------------------------------------------------------
__global__ __launch_bounds__(1024) void k_bucket(const int* __restrict__ label,
    int* __restrict__ counts, int* __restrict__ rank_g, int* __restrict__ offs,
    float* __restrict__ countsf, int* __restrict__ list) {
  __shared__ int lc[C_CLS], lf[C_CLS], loff[C_CLS], lcur[C_CLS];
  const int t = threadIdx.x;
  if (t < C_CLS) { lc[t] = 0; lf[t] = 0x7fffffff; lcur[t] = 0; }
  __syncthreads();
  #pragma unroll
  for (int q = 0; q < 16; ++q) {
    int i = q * 1024 + t;
    int c = label[i];
    atomicAdd(&lc[c], 1);
    atomicMin(&lf[c], i);
  }
  __syncthreads();
  if (t == 0) {
    int run = 0;
    for (int c = 0; c < C_CLS; ++c) { loff[c] = run; run += lc[c]; }
  }
  __syncthreads();
  if (t < C_CLS) {
    counts[t]  = lc[t];
    countsf[t] = (float)lc[t];
    offs[t]    = loff[t];
    // rank = stable double-argsort of first-occurrence
    int f = lf[t], r = 0;
    for (int c2 = 0; c2 < C_CLS; ++c2) {
      int f2 = lf[c2];
      r += (f2 < f) || (f2 == f && c2 < t);
    }
    rank_g[t] = r;
  }
  #pragma unroll
  for (int q = 0; q < 16; ++q) {
    int i = q * 1024 + t;
    int c = label[i];
    int pos = atomicAdd(&lcur[c], 1);
    list[loff[c] + pos] = i;
  }
}

// ---------------------------------------------------------------------------
// K2: per-class second moment M_c = sum_{i in c} x_i x_i^T (atomic merge into S
// buffer) + per-class column sums. 4 splits per class -> 128 blocks.
// Each thread owns an 8x8 register tile of the 128x128 output.
// ---------------------------------------------------------------------------
__global__ __launch_bounds__(256) void k_scatter(const float* __restrict__ feat,
    const int* __restrict__ counts, const int* __restrict__ offs,
    const int* __restrict__ list, float* __restrict__ M, float* __restrict__ colsum) {
  const int c = blockIdx.x >> 2, s = blockIdx.x & 3;
  const int n = counts[c], off = offs[c];
  const int beg = off + (n * s) / 4, end = off + (n * (s + 1)) / 4;
  __shared__ __align__(16) float ls[32 * 128];
  const int t = threadIdx.x;
  const int tr = t >> 4, tc = t & 15;
  float acc[8][8];
  #pragma unroll
  for (int i = 0; i < 8; ++i)
    #pragma unroll
    for (int j = 0; j < 8; ++j) acc[i][j] = 0.f;
  float cs = 0.f;
  const int col = t & 127, half = t >> 7;
  for (int base = beg; base < end; base += 32) {
    const int nb = min(32, end - base);
    __syncthreads();             // protect ls against previous-iter readers
    #pragma unroll
    for (int w = 0; w < 4; ++w) {
      int f4 = w * 256 + t;      // 0..1023 over 32 rows x 32 float4
      int r = f4 >> 5, c4 = f4 & 31;
      float4 v = make_float4(0.f, 0.f, 0.f, 0.f);
      if (r < nb) {
        int row = list[base + r];
        v = ((const float4*)(feat + (long)row * K_DIM))[c4];
      }
      ((float4*)ls)[f4] = v;     // zero-padded tail rows contribute nothing
    }
    __syncthreads();
    #pragma unroll
    for (int r0 = 0; r0 < 16; ++r0) cs += ls[(half * 16 + r0) * 128 + col];
    for (int r = 0; r < nb; ++r) {
      const float4* lr = (const float4*)(ls + r * 128);
      float4 A0 = lr[tr * 2], A1 = lr[tr * 2 + 1];
      float4 B0 = lr[tc * 2], B1 = lr[tc * 2 + 1];
      float av[8] = {A0.x, A0.y, A0.z, A0.w, A1.x, A1.y, A1.z, A1.w};
      float bv[8] = {B0.x, B0.y, B0.z, B0.w, B1.x, B1.y, B1.z, B1.w};
      #pragma unroll
      for (int i = 0; i < 8; ++i)
        #pragma unroll
        for (int j = 0; j < 8; ++j) acc[i][j] += av[i] * bv[j];
    }
  }
  float* Mc = M + c * 16384;
  #pragma unroll
  for (int i = 0; i < 8; ++i)
    #pragma unroll
    for (int j = 0; j < 8; ++j)
      atomicAdd(&Mc[(tr * 8 + i) * 128 + (tc * 8 + j)], acc[i][j]);
  atomicAdd(&colsum[c * 128 + col], cs);
}

// ---------------------------------------------------------------------------
// K3: mu = colsum/n ; S = M/n - mu mu^T + I (in place over the M buffer)
// ---------------------------------------------------------------------------
__global__ __launch_bounds__(256) void k_finalize(float* __restrict__ S,
    const float* __restrict__ colsum, const float* __restrict__ countsf,
    float* __restrict__ mu) {
  const int c = blockIdx.x, t = threadIdx.x;
  __shared__ __align__(16) float ml[128];
  const float n = countsf[c];
  if (t < 128) {
    float m = colsum[c * 128 + t] / n;
    ml[t] = m;
    mu[c * 128 + t] = m;
  }
  __syncthreads();
  float4* S4 = (float4*)(S + c * 16384);
  const float rn = 1.0f / n;
  #pragma unroll
  for (int q = 0; q < 16; ++q) {
    int f4 = q * 256 + t;
    int a = f4 >> 5, b = (f4 & 31) * 4;
    float4 v = S4[f4];
    float ma = ml[a];
    v.x = v.x * rn - ma * ml[b + 0] + ((a == b + 0) ? 1.f : 0.f);
    v.y = v.y * rn - ma * ml[b + 1] + ((a == b + 1) ? 1.f : 0.f);
    v.z = v.z * rn - ma * ml[b + 2] + ((a == b + 2) ? 1.f : 0.f);
    v.w = v.w * rn - ma * ml[b + 3] + ((a == b + 3) ? 1.f : 0.f);
    S4[f4] = v;
  }
}

// ---------------------------------------------------------------------------
// K4: symmetric sweep-operator inversion + log2-det, fully register-resident.
// Thread t of 256 holds 16 float4 = 64 elems: rows rq = 8q + (t>>5),
// cols [4*(t&31) .. +3]. Sweeping all pivots of SPD A yields -A^{-1};
// det = prod of pivots (all >= 1 because S >= I). One 512 B LDS row
// broadcast + 1 barrier per step; p-loop unrolled via template recursion so
// every register index is compile-time static (no scratch).
// ---------------------------------------------------------------------------
template<int P>
__device__ __forceinline__ void sweep_step(float4 (&A)[16], float (*vbuf)[128],
                                           int h, int c4i, float& lda) {
  constexpr int buf = P & 1;
  if (h == (P & 7)) ((float4*)vbuf[buf])[c4i] = A[P >> 3];   // export row P
  __syncthreads();
  const float d = vbuf[buf][P];
  lda += __log2f(d);
  const float dinv = 1.0f / d;
  float4 vc = ((const float4*)vbuf[buf])[c4i];
  float4 wc = make_float4(vc.x * dinv, vc.y * dinv, vc.z * dinv, vc.w * dinv);
  const bool colp = (c4i == (P >> 2));
  #pragma unroll
  for (int q = 0; q < 16; ++q) {
    const int rq = q * 8 + h;
    const float vr = vbuf[buf][rq];
    float4 nA;
    nA.x = A[q].x - vr * wc.x;
    nA.y = A[q].y - vr * wc.y;
    nA.z = A[q].z - vr * wc.z;
    nA.w = A[q].w - vr * wc.w;
    if (q == (P >> 3)) {             // compile-time q selection
      if (h == (P & 7)) nA = wc;     // row P: B[P][c] = v[c]/d
    }
    if (colp) {                      // col P: B[r][P] = v[r]/d ; diag: -1/d
      float cp = (rq == P) ? -dinv : vr * dinv;
      if constexpr ((P & 3) == 0)      nA.x = cp;
      else if constexpr ((P & 3) == 1) nA.y = cp;
      else if constexpr ((P & 3) == 2) nA.z = cp;
      else                             nA.w = cp;
    }
    A[q] = nA;
  }
}

template<int P>
struct SweepUnroll {
  __device__ static __forceinline__ void run(float4 (&A)[16], float (*vbuf)[128],
                                             int h, int c4i, float& lda) {
    sweep_step<P>(A, vbuf, h, c4i, lda);
    SweepUnroll<P + 1>::run(A, vbuf, h, c4i, lda);
  }
};
template<>
struct SweepUnroll<128> {
  __device__ static __forceinline__ void run(float4 (&)[16], float (*)[128],
                                             int, int, float&) {}
};

__global__ __launch_bounds__(256) void k_sweep(const float* __restrict__ S,
    float* __restrict__ INVg, float* __restrict__ ld2) {
  const int c = blockIdx.x, t = threadIdx.x;
  __shared__ __align__(16) float vbuf[2][128];
  const float4* S4 = (const float4*)(S + c * 16384);
  float4 A[16];
  #pragma unroll
  for (int q = 0; q < 16; ++q) A[q] = S4[q * 256 + t];
  float lda = 0.f;
  const int h = t >> 5, c4i = t & 31;
  SweepUnroll<0>::run(A, vbuf, h, c4i, lda);
  float4* O4 = (float4*)(INVg + c * 16384);
  #pragma unroll
  for (int q = 0; q < 16; ++q)
    O4[q * 256 + t] = make_float4(-A[q].x, -A[q].y, -A[q].z, -A[q].w);
  if (t == 0) ld2[c] = lda;          // v_log_f32 is log2 -> matches slogdet/ln2
}

// ---------------------------------------------------------------------------
// K5: pairwise tr+quad fused: sum_f inv_j[f] * (S_i[f] + diff[a]*diff[b]);
// kl = 0.5*(ld2[j]-ld2[i] - 128 + sum); masked atomic accumulate.
// ---------------------------------------------------------------------------
__global__ __launch_bounds__(256) void k_pairs(const float* __restrict__ S,
    const float* __restrict__ INVg, const float* __restrict__ mu,
    const float* __restrict__ ld2, const int* __restrict__ rank_g,
    float* __restrict__ klacc) {
  const int j = blockIdx.x, i = blockIdx.y;
  if (rank_g[i] > C_CLS - 2 || rank_g[j] < 1) return;
  __shared__ __align__(16) float dl[128];
  __shared__ float wsum[4];
  const int t = threadIdx.x;
  if (t < 128) dl[t] = mu[i * 128 + t] - mu[j * 128 + t];
  __syncthreads();
  const float4* Si4 = (const float4*)(S + i * 16384);
  const float4* Ij4 = (const float4*)(INVg + j * 16384);
  float s = 0.f;
  #pragma unroll
  for (int q = 0; q < 16; ++q) {
    int f4 = q * 256 + t;
    int a = f4 >> 5, b4 = f4 & 31;
    float da = dl[a];
    float4 db = ((const float4*)dl)[b4];
    float4 si = Si4[f4], ij = Ij4[f4];
    s += ij.x * (si.x + da * db.x);
    s += ij.y * (si.y + da * db.y);
    s += ij.z * (si.z + da * db.z);
    s += ij.w * (si.w + da * db.w);
  }
  #pragma unroll
  for (int off = 32; off > 0; off >>= 1) s += __shfl_xor(s, off);
  if ((t & 63) == 0) wsum[t >> 6] = s;
  __syncthreads();
  if (t == 0) {
    float tot = wsum[0] + wsum[1] + wsum[2] + wsum[3];
    float kl = 0.5f * ((ld2[j] - ld2[i]) - 128.0f + tot);
    atomicAdd(klacc, kl);
  }
}

// ---------------------------------------------------------------------------
// K6: out = klacc - sum(mu^2)
// ---------------------------------------------------------------------------
__global__ __launch_bounds__(256) void k_final(const float* __restrict__ mu,
    const float* __restrict__ klacc, float* __restrict__ out) {
  const int t = threadIdx.x;
  __shared__ float wsum[4];
  float s = 0.f;
  #pragma unroll
  for (int q = 0; q < 16; ++q) {
    float m = mu[q * 256 + t];
    s += m * m;
  }
  #pragma unroll
  for (int off = 32; off > 0; off >>= 1) s += __shfl_xor(s, off);
  if ((t & 63) == 0) wsum[t >> 6] = s;
  __syncthreads();
  if (t == 0) out[0] = klacc[0] - (wsum[0] + wsum[1] + wsum[2] + wsum[3]);
}

extern "C" void kernel_launch(void* const* d_in, const int* in_sizes, int n_in,
                              void* d_out, int out_size, void* d_ws, size_t ws_size,
                              hipStream_t stream) {
  const float* feat  = (const float*)d_in[0];
  const int*   label = (const int*)d_in[1];
  // d_in[2] (pan) is unused by the reference module.
  float* out = (float*)d_out;
  char*  ws  = (char*)d_ws;

  int*   counts  = (int*)(ws + O_COUNTS);
  int*   rank_g  = (int*)(ws + O_RANK);
  int*   offs    = (int*)(ws + O_OFFS);
  float* klacc   = (float*)(ws + O_KLACC);
  float* ld2     = (float*)(ws + O_LD2);
  float* countsf = (float*)(ws + O_COUNTSF);
  float* colsum  = (float*)(ws + O_COLSUM);
  float* mu      = (float*)(ws + O_MU);
  int*   list    = (int*)(ws + O_LIST);
  float* S       = (float*)(ws + O_S);
  float* INVg    = (float*)(ws + O_INV);

  hipMemsetAsync(ws, 0, 18432, stream);                 // header + colsum
  hipMemsetAsync(S, 0, C_CLS * 16384 * 4, stream);      // M accumulators

  k_bucket  <<<1,            1024, 0, stream>>>(label, counts, rank_g, offs, countsf, list);
  k_scatter <<<128,           256, 0, stream>>>(feat, counts, offs, list, S, colsum);
  k_finalize<<<C_CLS,         256, 0, stream>>>(S, colsum, countsf, mu);
  k_sweep   <<<C_CLS,         256, 0, stream>>>(S, INVg, ld2);
  k_pairs   <<<dim3(C_CLS, C_CLS), 256, 0, stream>>>(S, INVg, mu, ld2, rank_g, klacc);
  k_final   <<<1,             256, 0, stream>>>(mu, klacc, out);
}